// Round 7
// baseline (773.419 us; speedup 1.0000x reference)
//
#include <hip/hip_runtime.h>
#include <stdint.h>
#include <math.h>

#define TT 1024
#define FF 32
#define HH 64
#define CST 112   // f16 per Bst column: [h_enc 0..63 | h_dec 64..95] + pad

typedef unsigned int u32;
typedef _Float16 f16;
typedef __attribute__((ext_vector_type(8))) _Float16 half8;  // 8 fp16 = 4 VGPRs (MFMA A/B frag)
typedef __attribute__((ext_vector_type(4))) float v4f;       // MFMA C/D frag

#define L2E  1.44269504088896341f   // log2(e)
#define L2E2 2.88539008177792681f   // 2*log2(e)

// pre-scaled-input nonlinearities (scaling folded into weights/biases)
__device__ __forceinline__ float fsig_s(float s) {           // sigmoid(s/L2E)
    return __builtin_amdgcn_rcpf(1.f + __builtin_amdgcn_exp2f(-s));
}
__device__ __forceinline__ float ftanh_s(float s) {          // tanh(s/L2E2)
    return 2.f * __builtin_amdgcn_rcpf(1.f + __builtin_amdgcn_exp2f(-s)) - 1.f;
}

// load 8 consecutive fp32, scale, -> fp16 octet (RNE)
__device__ __forceinline__ half8 ld8h(const float* p, float sc) {
    float4 a = *(const float4*)p, b = *(const float4*)(p + 4);
    half8 r;
    r[0] = (f16)(a.x * sc); r[1] = (f16)(a.y * sc); r[2] = (f16)(a.z * sc); r[3] = (f16)(a.w * sc);
    r[4] = (f16)(b.x * sc); r[5] = (f16)(b.y * sc); r[6] = (f16)(b.z * sc); r[7] = (f16)(b.w * sc);
    return r;
}

// Round-7 = r6 + three changes driven by the closed issue model
// (per step-pair per SIMD: MFMA 36x19.4 = 700 cy, VALU 912 cy, measured
//  1721 = SUM not MAX -> co-resident blocks phase-locked, pipes never
//  interleave across blocks):
//  1. ANTIPHASE STAGGER: CU-sharing pairs are (i, i+256) under XCD
//     round-robin; odd-pair blocks s_sleep ~384cy at start so one block's
//     MFMA burst overlaps the other's VALU phase (sum -> max).
//  2. x AS MFMA C-OPERAND, ONE STEP AHEAD: acc_x = W_ih*x(tt+1) computed
//     during step tt (x known ahead), fed as C-in to the recurrent chain.
//     Enc dep chain 3->2 MFMA stages; x-staging lanes, Bst x-region and the
//     fp32 xst buffer all deleted (x lives as per-chunk fp16 xh16).
//  3. readfirstlane(w) -> scalar enc/dec branch: kills the 24 v_cndmask the
//     (tile<16 ? bf2 : bf3) ternary cost per step.

__global__ __launch_bounds__(256, 2)
void lstm_ae_mfma(const float* __restrict__ x,
                  const float* __restrict__ ewih, const float* __restrict__ ewhh,
                  const float* __restrict__ ebih, const float* __restrict__ ebhh,
                  const float* __restrict__ dwih, const float* __restrict__ dwhh,
                  const float* __restrict__ dbih, const float* __restrict__ dbhh,
                  float* __restrict__ out)
{
    const int b = blockIdx.x;
    const int t = threadIdx.x;
    const int w = t >> 6;        // wave 0..3
    const int wu = __builtin_amdgcn_readfirstlane(w);   // SGPR copy for scalar branches
    const int l = t & 63;
    const int q = l >> 4;        // quad: A/B k-group, D row-group
    const int n = l & 15;        // A row-in-tile / B+D column

    __shared__ __align__(16) f16 Bst[2][2][CST];   // [buf][col hi/lo][96+pad]
    __shared__ __align__(16) f16 xh16[2][64][32];  // per-chunk x, fp16, dbuf
    __shared__ __align__(16) f16 zp[8];            // zero page (odd-lane bx)

    // ---- persistent A fragments (fp32 -> fp16, gate-scaled) ----
    const float sc = ((n & 3) == 2) ? L2E2 : L2E;
    half8 af[6][3];
#pragma unroll
    for (int i = 0; i < 6; ++i) {
        int tile = w * 6 + i;
        if (tile < 16) {
            int r = (n & 3) * 64 + tile * 4 + (n >> 2);          // enc W row
            af[i][0] = ld8h(ewhh + r * 64 + q * 8, sc);          // k 0..31  (h_enc)
            af[i][1] = ld8h(ewhh + r * 64 + 32 + q * 8, sc);     // k 32..63 (h_enc)
            af[i][2] = ld8h(ewih + r * 32 + q * 8, sc);          // x (C-precompute)
        } else {
            int r = (n & 3) * 32 + (tile - 16) * 4 + (n >> 2);   // dec V row
            af[i][0] = ld8h(dwih + r * 64 + q * 8, sc);          // k 0..31  (h_enc)
            af[i][1] = ld8h(dwih + r * 64 + 32 + q * 8, sc);     // k 32..63 (h_enc)
            af[i][2] = ld8h(dwhh + r * 32 + q * 8, sc);          // k 64..95 (h_dec)
        }
    }

    // ---- lane-pair roles: pair s=n>>1 (<6) owns tile w*6+s; even=hi, odd=lo ----
    const int sel = n >> 1;
    const bool act = (n < 12);
    const int tile_s = w * 6 + (sel < 6 ? sel : 0);
    const bool is_enc = (tile_s < 16);
    const int u = is_enc ? (tile_s * 4 + q) : ((tile_s - 16) * 4 + q);
    const int wk1 = (n & 1) * CST + (is_enc ? u : 64 + u);       // h write offset

    float b0 = 0.f, b1 = 0.f, b2 = 0.f, b3 = 0.f, c_st = 0.f;
    if (act) {
        if (is_enc) {
            b0 = ebih[u]       + ebhh[u];
            b1 = ebih[64 + u]  + ebhh[64 + u];
            b2 = ebih[128 + u] + ebhh[128 + u];
            b3 = ebih[192 + u] + ebhh[192 + u];
        } else {
            b0 = dbih[u]      + dbhh[u];
            b1 = dbih[32 + u] + dbhh[32 + u];
            b2 = dbih[64 + u] + dbhh[64 + u];
            b3 = dbih[96 + u] + dbhh[96 + u];
        }
    }
    b0 *= L2E; b1 *= L2E; b2 *= L2E2; b3 *= L2E;

    // ---- prologue: zero Bst+zp, stage x chunk 0 as fp16 ----
    { u32* bz = (u32*)&Bst[0][0][0]; if (t < 2 * 2 * CST / 2) bz[t] = 0u; }
    if (t < 4) ((u32*)zp)[t] = 0u;
    const float* xb = x + (size_t)b * TT * FF;
    {
        float4 a0 = *(const float4*)(xb + t * 8);
        float4 a1 = *(const float4*)(xb + t * 8 + 4);
        half8 hx;
        hx[0] = (f16)a0.x; hx[1] = (f16)a0.y; hx[2] = (f16)a0.z; hx[3] = (f16)a0.w;
        hx[4] = (f16)a1.x; hx[5] = (f16)a1.y; hx[6] = (f16)a1.z; hx[7] = (f16)a1.w;
        *(half8*)&xh16[0][t >> 2][(t & 3) * 8] = hx;
    }
    __syncthreads();

    v4f zero = {0.f, 0.f, 0.f, 0.f};

    // ---- initial acc_x = W_ih * x[0] (enc tiles; dec tiles stay zero) ----
    v4f accx[6];
#pragma unroll
    for (int i = 0; i < 6; ++i) accx[i] = zero;
    {
        const f16* xpn = (n & 1) ? zp : &xh16[0][0][q * 8];
        half8 bx0 = *(const half8*)xpn;
#pragma unroll
        for (int i = 0; i < 6; ++i)
            if (wu * 6 + i < 16)
                accx[i] = __builtin_amdgcn_mfma_f32_16x16x32_f16(af[i][2], bx0, zero, 0, 0, 0);
    }

    // ---- antiphase stagger: CU-sharing pair is (b, b+256); delay one of them ----
    if ((b >> 8) & 1) asm volatile("s_sleep 6");

    for (int tt = 0; tt <= TT; ++tt) {
        const int p = tt & 1;

        // x chunk prefetch: issue loads now, cvt+LDS-write just before barrier
        float4 px0, px1;
        const int cn = (tt >> 6) + 1;
        const bool pf = ((tt & 63) == 0) && (cn < 16);
        if (pf) {
            px0 = *(const float4*)(xb + cn * 2048 + t * 8);
            px1 = *(const float4*)(xb + cn * 2048 + t * 8 + 4);
        }

        // ---- B fragments (recurrent first so bf0 returns first) ----
        const f16* Bp = &Bst[p][0][0];
        const int cb = (n & 1) * CST + q * 8;
        half8 bf0 = *(const half8*)(Bp + cb);          // h_enc 0..31
        half8 bf1 = *(const half8*)(Bp + cb + 32);     // h_enc 32..63
        half8 bf3 = *(const half8*)(Bp + cb + 64);     // h_dec
        const int sx = tt + 1;                          // next step's x
        const f16* xpn = (n & 1) ? zp : &xh16[(sx >> 6) & 1][sx & 63][q * 8];
        half8 bx = *(const half8*)xpn;

        v4f acc[6];
#pragma unroll
        for (int i = 0; i < 6; ++i) {
            v4f s1 = __builtin_amdgcn_mfma_f32_16x16x32_f16(af[i][0], bf0, accx[i], 0, 0, 0);
            v4f s2 = __builtin_amdgcn_mfma_f32_16x16x32_f16(af[i][1], bf1, s1, 0, 0, 0);
            if (wu * 6 + i < 16) {          // SCALAR branch: enc tile
                acc[i] = s2;                //   2-stage chain; refresh acc_x off-path
                accx[i] = __builtin_amdgcn_mfma_f32_16x16x32_f16(af[i][2], bx, zero, 0, 0, 0);
            } else {                        // dec tile: 3rd recurrent stage (h_dec)
                acc[i] = __builtin_amdgcn_mfma_f32_16x16x32_f16(af[i][2], bf3, s2, 0, 0, 0);
            }
        }

        // ---- select this pair's tile (cndmask chain, masks hoisted) ----
        v4f u_ = acc[0];
#pragma unroll
        for (int i = 1; i < 6; ++i) if (sel == i) u_ = acc[i];

        // ---- hi+lo reduce: lane n <-> n^1 via DPP quad_perm [1,0,3,2] ----
        v4f s_;
#pragma unroll
        for (int e = 0; e < 4; ++e) {
            int tmp = __builtin_amdgcn_update_dpp(0, __float_as_int(u_[e]), 0xB1, 0xF, 0xF, true);
            s_[e] = u_[e] + __int_as_float(tmp);
        }

        // ---- unit update (pre-scaled domain) + h write to buf p^1 ----
        f16* Bw = &Bst[p ^ 1][0][0];
        if (act && (is_enc ? (tt < TT) : (tt >= 1))) {
            float i_ = fsig_s(s_[0] + b0);
            float f_ = fsig_s(s_[1] + b1);
            float g_ = ftanh_s(s_[2] + b2);
            float o_ = fsig_s(s_[3] + b3);
            c_st = f_ * c_st + L2E2 * (i_ * g_);
            float h = o_ * ftanh_s(c_st);
            f16 hi = (f16)h;
            f16 lo = (f16)(h - (float)hi);
            Bw[wk1] = (n & 1) ? lo : hi;
            if (!is_enc && !(n & 1))
                out[(size_t)b * TT * FF + (size_t)(tt - 1) * FF + u] = h;
        }

        // deferred x-chunk cvt+write (loads in flight across MFMA + update)
        if (pf) {
            half8 hx;
            hx[0] = (f16)px0.x; hx[1] = (f16)px0.y; hx[2] = (f16)px0.z; hx[3] = (f16)px0.w;
            hx[4] = (f16)px1.x; hx[5] = (f16)px1.y; hx[6] = (f16)px1.z; hx[7] = (f16)px1.w;
            *(half8*)&xh16[cn & 1][t >> 2][(t & 3) * 8] = hx;
        }

        // ---- raw barrier: drain LDS only; out[] stores stay in flight ----
        asm volatile("s_waitcnt lgkmcnt(0)" ::: "memory");
        __builtin_amdgcn_s_barrier();
        __builtin_amdgcn_sched_barrier(0);
    }
}

extern "C" void kernel_launch(void* const* d_in, const int* in_sizes, int n_in,
                              void* d_out, int out_size, void* d_ws, size_t ws_size,
                              hipStream_t stream) {
    (void)in_sizes; (void)n_in; (void)out_size; (void)d_ws; (void)ws_size;
    lstm_ae_mfma<<<512, 256, 0, stream>>>((const float*)d_in[0],
                                          (const float*)d_in[1], (const float*)d_in[2],
                                          (const float*)d_in[3], (const float*)d_in[4],
                                          (const float*)d_in[5], (const float*)d_in[6],
                                          (const float*)d_in[7], (const float*)d_in[8],
                                          (float*)d_out);
}

// Round 8
// 712.825 us; speedup vs baseline: 1.0850x; 1.0850x over previous
//
#include <hip/hip_runtime.h>
#include <stdint.h>
#include <math.h>

#define TT 1024
#define FF 32
#define HH 64

typedef unsigned int u32;
typedef _Float16 f16;
typedef __attribute__((ext_vector_type(8))) _Float16 half8;  // 8 fp16 = 4 VGPRs (MFMA A/B frag)
typedef __attribute__((ext_vector_type(4))) float v4f;       // MFMA C/D frag

#define L2E  1.44269504088896341f   // log2(e)
#define L2E2 2.88539008177792681f   // 2*log2(e)

// pre-scaled-input nonlinearities (scaling folded into weights/biases)
__device__ __forceinline__ float fsig_s(float s) {           // sigmoid(s/L2E)
    return __builtin_amdgcn_rcpf(1.f + __builtin_amdgcn_exp2f(-s));
}
__device__ __forceinline__ float ftanh_s(float s) {          // tanh(s/L2E2)
    return 2.f * __builtin_amdgcn_rcpf(1.f + __builtin_amdgcn_exp2f(-s)) - 1.f;
}

// load 8 consecutive fp32, scale, -> fp16 octet (RNE)
__device__ __forceinline__ half8 ld8h(const float* p, float sc) {
    float4 a = *(const float4*)p, b = *(const float4*)(p + 4);
    half8 r;
    r[0] = (f16)(a.x * sc); r[1] = (f16)(a.y * sc); r[2] = (f16)(a.z * sc); r[3] = (f16)(a.w * sc);
    r[4] = (f16)(b.x * sc); r[5] = (f16)(b.y * sc); r[6] = (f16)(b.z * sc); r[7] = (f16)(b.w * sc);
    return r;
}

// Round-8 = r6 EXACTLY (proven 731 us, conflict-free CST=160 layout: col1 at
// bank 16, disjoint from col0 banks 0-15) + issue-level-only changes:
//  1. ANTIPHASE, SUSTAINED: r7's stagger test was confounded by its own
//     bank-conflict regression (CST=112 put col1 at bank 24 -> 10x conflicts).
//     Clean test here: initial s_sleep 7 (~448cy = half step) for the
//     CU-partner block (pairs (b, b+256) under XCD round-robin), plus
//     s_setprio(1) around the 18-MFMA cluster so the issue arbiter
//     PERSISTENTLY favors the wave in its MFMA phase (T5 mechanism; the two
//     waves/SIMD belong to independent blocks, unlike m190's lockstep null).
//     Target: per-SIMD step-pair cost sum(MFMA 700 + VALU 912) -> max(~950).
//  2. readfirstlane(w) scalar branch for the (tile<16 ? bf2 : bf3) operand
//     select: -24 v_cndmask per step (kept from r7; not the regression source).
//  3. scalar wu>=2 gate on the out[] store block: pure-enc waves 0,1 skip it.

__global__ __launch_bounds__(256, 2)
void lstm_ae_mfma(const float* __restrict__ x,
                  const float* __restrict__ ewih, const float* __restrict__ ewhh,
                  const float* __restrict__ ebih, const float* __restrict__ ebhh,
                  const float* __restrict__ dwih, const float* __restrict__ dwhh,
                  const float* __restrict__ dbih, const float* __restrict__ dbhh,
                  float* __restrict__ out)
{
    const int b = blockIdx.x;
    const int t = threadIdx.x;
    const int w = t >> 6;        // wave 0..3
    const int wu = __builtin_amdgcn_readfirstlane(w);   // SGPR copy, scalar branches
    const int l = t & 63;
    const int q = l >> 4;        // quad: A/B k-group, D row-group
    const int n = l & 15;        // A row-in-tile / B+D column

    __shared__ __align__(16) f16 Bst[2][2][160];     // [buf][col hi/lo][K(128)+pad]
    __shared__ __align__(16) float xst[2][2048];     // x 64-step chunks, fp32, dbuf

    // ---- persistent A fragments (fp32 -> fp16, gate-scaled) ----
    const float sc = ((n & 3) == 2) ? L2E2 : L2E;
    half8 af[6][3];
#pragma unroll
    for (int i = 0; i < 6; ++i) {
        int tile = w * 6 + i;
        if (tile < 16) {
            int r = (n & 3) * 64 + tile * 4 + (n >> 2);          // enc W row
            af[i][0] = ld8h(ewhh + r * 64 + q * 8, sc);          // k 0..31  (h_enc)
            af[i][1] = ld8h(ewhh + r * 64 + 32 + q * 8, sc);     // k 32..63 (h_enc)
            af[i][2] = ld8h(ewih + r * 32 + q * 8, sc);          // k 64..95 (x)
        } else {
            int r = (n & 3) * 32 + (tile - 16) * 4 + (n >> 2);   // dec V row
            af[i][0] = ld8h(dwih + r * 64 + q * 8, sc);          // k 0..31  (h_enc)
            af[i][1] = ld8h(dwih + r * 64 + 32 + q * 8, sc);     // k 32..63 (h_enc)
            af[i][2] = ld8h(dwhh + r * 32 + q * 8, sc);          // k 96..127 (h_dec)
        }
    }

    // ---- lane-pair roles: pair s=n>>1 (<6) owns tile w*6+s; even=hi, odd=lo ----
    const int sel = n >> 1;                          // 0..7
    const bool act = (n < 12);                       // 6 pairs active
    const int tile_s = w * 6 + (sel < 6 ? sel : 0);  // clamped for inactive lanes
    const bool is_enc = (tile_s < 16);
    const int u = is_enc ? (tile_s * 4 + q) : ((tile_s - 16) * 4 + q);

    float b0 = 0.f, b1 = 0.f, b2 = 0.f, b3 = 0.f, c_st = 0.f;
    if (act) {
        if (is_enc) {
            b0 = ebih[u]       + ebhh[u];
            b1 = ebih[64 + u]  + ebhh[64 + u];
            b2 = ebih[128 + u] + ebhh[128 + u];
            b3 = ebih[192 + u] + ebhh[192 + u];
        } else {
            b0 = dbih[u]      + dbhh[u];
            b1 = dbih[32 + u] + dbhh[32 + u];
            b2 = dbih[64 + u] + dbhh[64 + u];
            b3 = dbih[96 + u] + dbhh[96 + u];
        }
    }
    b0 *= L2E; b1 *= L2E; b2 *= L2E2; b3 *= L2E;

    // ---- prologue: zero both Bst buffers, stage x chunk 0, x[0] into buf0 ----
    { u32* bz = (u32*)&Bst[0][0][0]; for (int i2 = t; i2 < 2 * 2 * 160 / 2; i2 += 256) bz[i2] = 0u; }
    const float* xb = x + (size_t)b * TT * FF;
    *(float4*)&xst[0][t * 8]     = *(const float4*)(xb + t * 8);
    *(float4*)&xst[0][t * 8 + 4] = *(const float4*)(xb + t * 8 + 4);
    __syncthreads();
    if (t >= 96 && t < 128) Bst[0][0][64 + (t - 96)] = (f16)xst[0][t - 96];
    __syncthreads();

    // ---- antiphase stagger: CU-sharing pair is (b, b+256); delay one of them ----
    if ((b >> 8) & 1) asm volatile("s_sleep 7");

    for (int tt = 0; tt <= TT; ++tt) {
        const int p = tt & 1;

        // x chunk prefetch: issue loads now, write LDS just before the barrier
        float4 px0, px1;
        const int cn = (tt >> 6) + 1;
        const bool pf = ((tt & 63) == 0) && (cn < 16);
        if (pf) {
            px0 = *(const float4*)(xb + cn * 2048 + t * 8);
            px1 = *(const float4*)(xb + cn * 2048 + t * 8 + 4);
        }

        // ---- B fragments (col = n&1 replicated, broadcast reads) ----
        const f16* Bp = &Bst[p][0][0];
        const int cb = (n & 1) * 160 + q * 8;
        half8 bf0 = *(const half8*)(Bp + cb);
        half8 bf1 = *(const half8*)(Bp + cb + 32);
        half8 bf2 = *(const half8*)(Bp + cb + 64);
        half8 bf3 = *(const half8*)(Bp + cb + 96);

        v4f zero = {0.f, 0.f, 0.f, 0.f};
        v4f acc[6];
        // MFMA cluster under raised priority: the wave currently in its MFMA
        // phase wins issue arbitration -> sustains antiphase vs partner block.
        __builtin_amdgcn_s_setprio(1);
        // stage 1: bf0 (first LDS return) -- MFMAs start at lgkmcnt(3)
#pragma unroll
        for (int i = 0; i < 6; ++i)
            acc[i] = __builtin_amdgcn_mfma_f32_16x16x32_f16(af[i][0], bf0, zero, 0, 0, 0);
        // stage 2: bf1
#pragma unroll
        for (int i = 0; i < 6; ++i)
            acc[i] = __builtin_amdgcn_mfma_f32_16x16x32_f16(af[i][1], bf1, acc[i], 0, 0, 0);
        // stage 3: x (enc tiles) or h_dec (dec tiles) -- SCALAR select via wu
#pragma unroll
        for (int i = 0; i < 6; ++i) {
            half8 bsel;
            if (wu * 6 + i < 16) bsel = bf2; else bsel = bf3;
            acc[i] = __builtin_amdgcn_mfma_f32_16x16x32_f16(af[i][2], bsel, acc[i], 0, 0, 0);
        }
        __builtin_amdgcn_s_setprio(0);

        // ---- select this pair's tile (cndmask chain, static indices) ----
        v4f u_ = acc[0];
#pragma unroll
        for (int i = 1; i < 6; ++i) if (sel == i) u_ = acc[i];

        // ---- hi+lo reduce: lane n <-> n^1 via DPP quad_perm [1,0,3,2] ----
        v4f s_;
#pragma unroll
        for (int e = 0; e < 4; ++e) {
            int tmp = __builtin_amdgcn_update_dpp(0, __float_as_int(u_[e]), 0xB1, 0xF, 0xF, true);
            s_[e] = u_[e] + __int_as_float(tmp);
        }

        // ---- unit update (pre-scaled domain) + h write to buf p^1 ----
        f16* Bw = &Bst[p ^ 1][0][0];
        if (act && (is_enc ? (tt < TT) : (tt >= 1))) {
            float i_ = fsig_s(s_[0] + b0);
            float f_ = fsig_s(s_[1] + b1);
            float g_ = ftanh_s(s_[2] + b2);
            float o_ = fsig_s(s_[3] + b3);
            c_st = f_ * c_st + L2E2 * (i_ * g_);
            float h = o_ * ftanh_s(c_st);
            f16 hi = (f16)h;
            f16 lo = (f16)(h - (float)hi);
            const int kk = is_enc ? u : (96 + u);
            Bw[(n & 1) * 160 + kk] = (n & 1) ? lo : hi;
            if (wu >= 2) {                       // scalar: only waves 2,3 hold dec tiles
                if (!is_enc && !(n & 1))
                    out[(size_t)b * TT * FF + (size_t)(tt - 1) * FF + u] = h;
            }
        } else if (n == 12 || n == 13) {        // stage x for enc step tt+1
            int st = tt + 1;
            if (st < TT) {
                int j = w * 8 + q * 2 + (n - 12);
                Bw[64 + j] = (f16)xst[(st >> 6) & 1][(st & 63) * 32 + j];
            }
        }

        // deferred x-chunk prefetch write (loads in flight across MFMA + update)
        if (pf) {
            *(float4*)&xst[cn & 1][t * 8]     = px0;
            *(float4*)&xst[cn & 1][t * 8 + 4] = px1;
        }

        // ---- raw barrier: drain LDS only; out[] stores stay in flight ----
        asm volatile("s_waitcnt lgkmcnt(0)" ::: "memory");
        __builtin_amdgcn_s_barrier();
        __builtin_amdgcn_sched_barrier(0);
    }
}

extern "C" void kernel_launch(void* const* d_in, const int* in_sizes, int n_in,
                              void* d_out, int out_size, void* d_ws, size_t ws_size,
                              hipStream_t stream) {
    (void)in_sizes; (void)n_in; (void)out_size; (void)d_ws; (void)ws_size;
    lstm_ae_mfma<<<512, 256, 0, stream>>>((const float*)d_in[0],
                                          (const float*)d_in[1], (const float*)d_in[2],
                                          (const float*)d_in[3], (const float*)d_in[4],
                                          (const float*)d_in[5], (const float*)d_in[6],
                                          (const float*)d_in[7], (const float*)d_in[8],
                                          (float*)d_out);
}